// Round 5
// baseline (147.729 us; speedup 1.0000x reference)
//
#include <hip/hip_runtime.h>
#include <stdint.h>
#include <math.h>

#define SLEN 512
#define NT 48
#define TAG_START 46
#define TAG_STOP 47

typedef float v2f __attribute__((ext_vector_type(2)));
typedef float v4f __attribute__((ext_vector_type(4)));

typedef const uint32_t __attribute__((address_space(1)))* gptr_t;
typedef uint32_t __attribute__((address_space(3)))* lptr_t;

__device__ __forceinline__ float bcastf(float v, int l) {
  return __int_as_float(__builtin_amdgcn_readlane(__float_as_int(v), l));
}
__device__ __forceinline__ void gload16(const float* g, float* l) {
  __builtin_amdgcn_global_load_lds((gptr_t)(uintptr_t)g, (lptr_t)(uintptr_t)l,
                                   16, 0, 0);
}

// One wave per batch. Lane j owns tag j. State linear: q_j = exp(alpha_j - C).
// Broadcast of q for the matvec goes through LDS (1 ds_write + 12 uniform
// ds_read_b128 per step) -- no per-step readlane/SGPR traffic, no inline asm.
__global__ __launch_bounds__(64) void crf_fwd_kernel(
    const float* __restrict__ em, const int* __restrict__ tags,
    const int* __restrict__ mask, const float* __restrict__ Tr,
    float* __restrict__ ws) {
  const int b = blockIdx.x;
  const int lane = threadIdx.x;
  __shared__ __align__(16) float lem[2][64 * NT + 16];  // dbuf emission chunks
  __shared__ __align__(16) float qbuf[64];

  // length = sum(mask row)  (prefix mask)
  const int* mrow = mask + (size_t)b * SLEN;
  int lc = 0;
  for (int t = lane; t < SLEN; t += 64) lc += mrow[t];
#pragma unroll
  for (int d = 32; d >= 1; d >>= 1) lc += __shfl_xor(lc, d);
  const int len = lc;

  // E[i][lane] = exp(T[i][lane]) as float2 pairs (i even/odd interleave).
  // exp(-10000) -> exactly 0 reproduces the NEG_INF barriers.
  v2f EcA[12], EcB[12];
#pragma unroll
  for (int k = 0; k < 12; ++k) {
    float e0 = (lane < NT) ? __expf(Tr[(4 * k + 0) * NT + lane]) : 0.f;
    float e1 = (lane < NT) ? __expf(Tr[(4 * k + 1) * NT + lane]) : 0.f;
    float e2 = (lane < NT) ? __expf(Tr[(4 * k + 2) * NT + lane]) : 0.f;
    float e3 = (lane < NT) ? __expf(Tr[(4 * k + 3) * NT + lane]) : 0.f;
    v2f a; a.x = e0; a.y = e1;
    v2f c; c.x = e2; c.y = e3;
    EcA[k] = a;
    EcB[k] = c;
  }

  float q = (lane == TAG_START) ? 1.0f : 0.0f;
  int cbits = 0;
  const float* embase = em + (size_t)b * SLEN * NT;

  auto dostep = [&](float x) {
    qbuf[lane] = q;  // ds_write; same-wave LDS pipe is in-order vs reads below
    v2f sA = {0.f, 0.f}, sB = {0.f, 0.f};
#pragma unroll
    for (int k = 0; k < 12; ++k) {
      const v4f qv = *(const v4f*)(qbuf + 4 * k);  // uniform addr -> broadcast
      v2f lo; lo.x = qv.x; lo.y = qv.y;
      v2f hi; hi.x = qv.z; hi.y = qv.w;
      sA = lo * EcA[k] + sA;  // fp-contract -> (pk_)fma, all-VGPR
      sB = hi * EcB[k] + sB;
    }
    q = ((sA.x + sA.y) + (sB.x + sB.y)) * x;
  };

  auto renorm = [&]() {  // shared power-of-2 rescale every 4 steps
    float mx = fmaxf(fmaxf(bcastf(q, 5), bcastf(q, 21)),
                     fmaxf(bcastf(q, 37), 1e-30f));
    int ex;
    (void)frexpf(mx, &ex);
    q = ldexpf(q, -ex);
    cbits += ex;
  };

  const int nchunks = (len + 63) >> 6;
#pragma unroll
  for (int k = 0; k < 12; ++k)  // prefetch chunk 0 -> buf 0
    gload16(embase + k * 256 + lane * 4, &lem[0][k * 256]);

  for (int c = 0; c < nchunks; ++c) {
    asm volatile("s_waitcnt vmcnt(0)" ::: "memory");
    if (c + 1 < nchunks) {  // prefetch next chunk into other buffer
      const float* src = embase + (size_t)(c + 1) * 64 * NT;
#pragma unroll
      for (int k = 0; k < 12; ++k)
        gload16(src + k * 256 + lane * 4, &lem[(c + 1) & 1][k * 256]);
    }
    const float* buf = lem[c & 1];
    const int tend = (len - c * 64 < 64) ? (len - c * 64) : 64;
    int tt = 0;
    for (; tt + 4 <= tend; tt += 4) {
      // e-loads + exp precomputed off the dependency chain
      float x0 = __expf(buf[(tt + 0) * NT + lane]);
      float x1 = __expf(buf[(tt + 1) * NT + lane]);
      float x2 = __expf(buf[(tt + 2) * NT + lane]);
      float x3 = __expf(buf[(tt + 3) * NT + lane]);
      dostep(x0);
      dostep(x1);
      dostep(x2);
      dostep(x3);
      renorm();
    }
    for (; tt < tend; ++tt) dostep(__expf(buf[tt * NT + lane]));
    renorm();
  }

  // logZ = cbits*ln2 + LSE_j(log q_j + T[STOP][j])
  float lq = (q > 0.f) ? __logf(q) : -__builtin_inff();
  float term = (lane < NT) ? lq + Tr[TAG_STOP * NT + lane] : -__builtin_inff();
  float m2 = term;
#pragma unroll
  for (int d = 32; d >= 1; d >>= 1) m2 = fmaxf(m2, __shfl_xor(m2, d));
  float ex2 = (lane < NT) ? __expf(term - m2) : 0.0f;
#pragma unroll
  for (int d = 32; d >= 1; d >>= 1) ex2 += __shfl_xor(ex2, d);
  const float logZ = m2 + __logf(ex2) + (float)cbits * 0.69314718055994531f;

  // gold score
  const int* trow = tags + (size_t)b * SLEN;
  float g = 0.f;
  for (int t = lane; t < len; t += 64) {
    const int tag = trow[t];
    const int prev = (t == 0) ? TAG_START : trow[t - 1];
    g += Tr[tag * NT + prev] + embase[(size_t)t * NT + tag];
  }
#pragma unroll
  for (int d = 32; d >= 1; d >>= 1) g += __shfl_xor(g, d);

  if (lane == 0) {
    const int last = trow[len - 1];
    ws[b] = logZ - (g + Tr[TAG_STOP * NT + last]);
  }
}

// Deterministic tree-mean over B values (no atomics).
__global__ void crf_reduce_kernel(const float* __restrict__ ws,
                                  float* __restrict__ out, int n) {
  const int tid = threadIdx.x;
  float v = (tid < n) ? ws[tid] : 0.f;
#pragma unroll
  for (int d = 32; d >= 1; d >>= 1) v += __shfl_xor(v, d);
  __shared__ float part[16];
  if ((tid & 63) == 0) part[tid >> 6] = v;
  __syncthreads();
  if (tid == 0) {
    float s = 0.f;
    for (int i = 0; i < 16; ++i) s += part[i];
    out[0] = s / (float)n;
  }
}

extern "C" void kernel_launch(void* const* d_in, const int* in_sizes, int n_in,
                              void* d_out, int out_size, void* d_ws, size_t ws_size,
                              hipStream_t stream) {
  const float* em = (const float*)d_in[0];
  const int* tags = (const int*)d_in[1];
  const int* mask = (const int*)d_in[2];
  const float* Tr = (const float*)d_in[3];
  const int B = in_sizes[0] / (SLEN * NT);  // 1024

  float* ws = (float*)d_ws;  // B floats
  crf_fwd_kernel<<<B, 64, 0, stream>>>(em, tags, mask, Tr, ws);
  crf_reduce_kernel<<<1, 1024, 0, stream>>>(ws, (float*)d_out, B);
}